// Round 12
// baseline (888.310 us; speedup 1.0000x reference)
//
#include <hip/hip_runtime.h>
#include <hip/hip_cooperative_groups.h>

namespace cg = cooperative_groups;

#define N_NODES 50000
#define N_EDGES 800000
#define F_IN    32
#define F_OUT   64
#define PERIODS 12
#define C_FEAT  160   // [X, Tx1o, Tx1i, Tx2o, Tx2i] each 32 channels

#define NKEY    (2 * N_NODES)    // 100000 combined keys: fwd=col, rev=N+row
#define NBIN    782              // ceil(100000/128) — 128 keys per bin
#define NBLK_A  128
#define EPB     (N_EDGES / NBLK_A)   // 6250 edges per A-block (exact)
#define TOT     (2 * N_EDGES)        // 1.6M CSR entries
#define SCANA_N (NBIN * NBLK_A)      // 100096 = 391*256 exactly
#define SCANA_NB 391
#define KPB     16                   // keys per gather block (16-lane groups)
#define NBLK_DIR (N_NODES / KPB)     // 3125 gather blocks per direction
#define NF      ((size_t)N_NODES * F_IN)
#define PREP_BLKS ((128 * C_FEAT) / 256)   // 80

typedef __attribute__((ext_vector_type(8))) short s16x8;
typedef __attribute__((ext_vector_type(4))) float f32x4;

static __device__ __forceinline__ ushort f2bf(float f) {
    unsigned u = __float_as_uint(f);
    unsigned r = (u + 0x7FFFu + ((u >> 16) & 1u)) >> 16;   // RNE
    return (ushort)r;
}
static __device__ __forceinline__ float bfLO(unsigned h) {   // low bf16 channel
    return __uint_as_float(h << 16);
}
static __device__ __forceinline__ float bfHI(unsigned h) {   // high bf16 channel
    return __uint_as_float(h & 0xffff0000u);
}

// ---------------------------------------------------------------------------
// ONE cooperative kernel for the whole CSR build + table prep.
// Grid = NBIN (782) blocks x 256. Phases separated by grid.sync():
//  0: edge histogram into 782 coarse bins (vb<128) + weight transpose (vb<208)
//  1: per-256 exclusive scan of hist (vb<391)
//  2: scan of 391 block sums (vb==0; two-segment ping-pong over 512)
//  3: multi-split edges -> binned items (vb<128)
//  4: per-bin counting sort -> csr/off + degree sums -> inv (all 782 vbs)
//  5: pre-scaled + raw bf16 X tables (grid-stride)   [overwrites binned: OK]
// ---------------------------------------------------------------------------
__global__ __launch_bounds__(256) void k_build(
        const int* __restrict__ ei, const float* __restrict__ ew,
        const float* __restrict__ wz, const float* __restrict__ wh,
        ushort* __restrict__ Wt,
        int* __restrict__ hist, int* __restrict__ scanA, int* __restrict__ bsum,
        uint2* __restrict__ binned, int* __restrict__ csr,
        int* __restrict__ off, float* __restrict__ inv,
        const float* __restrict__ X,
        ushort* __restrict__ Xso, ushort* __restrict__ Xsi,
        ushort* __restrict__ Xb) {
    cg::grid_group grid = cg::this_grid();
    __shared__ int S[1024];                    // 4 KB, reused every phase
    int tid = threadIdx.x, vb = blockIdx.x;

    // ---- phase 0: histogram + weight prep ----
    if (vb < NBLK_A) {
        for (int i = tid; i < NBIN; i += 256) S[i] = 0;
        __syncthreads();
        int e0 = vb * EPB;
        for (int i = tid; i < EPB; i += 256) {
            int e = e0 + i;
            int r = ei[e];
            int c = ei[N_EDGES + e];
            atomicAdd(&S[c >> 7], 1);
            atomicAdd(&S[(N_NODES + r) >> 7], 1);
        }
        __syncthreads();
        for (int i = tid; i < NBIN; i += 256) hist[i * NBLK_A + vb] = S[i];
    } else if (vb < NBLK_A + PREP_BLKS) {
        int t = (vb - NBLK_A) * 256 + tid;     // 0..20479 = 128*160
        int o = t / C_FEAT;
        int k = t % C_FEAT;
        int seg = k >> 5;
        int cc  = k & 31;
        const float* src = (o < 64) ? wz : wh;
        int oo = o & 63;
        float val;
        if (seg == 0)      val = src[(0 * 96 + cc) * 64 + oo] + src[(3 * 96 + cc) * 64 + oo];
        else if (seg == 1) val = src[(1 * 96 + cc) * 64 + oo];
        else if (seg == 2) val = src[(4 * 96 + cc) * 64 + oo];
        else if (seg == 3) val = src[(2 * 96 + cc) * 64 + oo];
        else               val = src[(5 * 96 + cc) * 64 + oo];
        Wt[t] = f2bf(val);
    }
    __threadfence();
    grid.sync();

    // ---- phase 1: scan1 ----
    if (vb < SCANA_NB) {
        int g = vb * 256 + tid;
        int v = hist[g];                       // SCANA_N = 391*256 exactly
        int orig = v;
        S[tid] = v;
        __syncthreads();
        for (int d = 1; d < 256; d <<= 1) {
            int t2 = (tid >= d) ? S[tid - d] : 0;
            __syncthreads();
            S[tid] += t2;
            __syncthreads();
        }
        scanA[g] = S[tid] - orig;              // exclusive, block-local
        if (tid == 255) bsum[vb] = S[tid];
    }
    __threadfence();
    grid.sync();

    // ---- phase 2: scan2 (vb==0), 391 sums, ping-pong over 512 slots ----
    if (vb == 0) {
        int* a = S;
        int* b = S + 512;
        int o0 = (tid < SCANA_NB) ? bsum[tid] : 0;
        int o1 = (tid + 256 < SCANA_NB) ? bsum[tid + 256] : 0;
        a[tid] = o0;
        a[tid + 256] = o1;
        __syncthreads();
        for (int d = 1; d < 512; d <<= 1) {
            int i1 = tid + 256;
            int v0 = a[tid] + ((tid >= d) ? a[tid - d] : 0);
            int v1 = a[i1] + a[i1 - d];        // i1 >= 256 >= d always when d<=256
            __syncthreads();
            b[tid] = v0;
            b[i1]  = v1;
            __syncthreads();
            int* tmp = a; a = b; b = tmp;
        }
        if (tid < SCANA_NB) bsum[tid] = a[tid] - o0;                 // exclusive
        if (tid + 256 < SCANA_NB) bsum[tid + 256] = a[tid + 256] - o1;
    }
    __threadfence();
    grid.sync();

    // ---- phase 3: multi-split ----
    if (vb < NBLK_A) {
        for (int i = tid; i < NBIN; i += 256) {
            int idx = i * NBLK_A + vb;
            S[i] = scanA[idx] + bsum[idx >> 8];
        }
        __syncthreads();
        int e0 = vb * EPB;
        for (int i = tid; i < EPB; i += 256) {
            int e = e0 + i;
            int r = ei[e];
            int c = ei[N_EDGES + e];
            unsigned wb = __float_as_uint(ew[e]);
            int p1 = atomicAdd(&S[c >> 7], 1);
            binned[p1] = make_uint2((unsigned)((c & 127) | (r << 7)), wb);
            int k2 = N_NODES + r;
            int p2 = atomicAdd(&S[k2 >> 7], 1);
            binned[p2] = make_uint2((unsigned)((k2 & 127) | (c << 7)), wb);
        }
    }
    __threadfence();
    grid.sync();

    // ---- phase 4: per-bin counting sort (vb = bin id, all 782) ----
    {
        int* cnt = S;
        int* sc  = S + 128;
        int* cur = S + 256;
        float* deg = (float*)(S + 384);
        int i0 = vb * NBLK_A;
        int base = scanA[i0] + bsum[i0 >> 8];
        int end;
        if (vb + 1 < NBIN) {
            int i1 = (vb + 1) * NBLK_A;
            end = scanA[i1] + bsum[i1 >> 8];
        } else end = TOT;
        if (tid < 128) { cnt[tid] = 0; deg[tid] = 0.0f; }
        __syncthreads();
        uint2 it[12];
#pragma unroll
        for (int k = 0; k < 12; ++k) {
            int i = base + tid + k * 256;
            if (i < end) it[k] = binned[i];
        }
#pragma unroll
        for (int k = 0; k < 12; ++k) {
            int i = base + tid + k * 256;
            if (i < end) {
                int kl = (int)(it[k].x & 127);
                atomicAdd(&cnt[kl], 1);
                atomicAdd(&deg[kl], __uint_as_float(it[k].y));
            }
        }
        for (int i = base + 3072 + tid; i < end; i += 256) {   // overflow path
            uint2 e = binned[i];
            atomicAdd(&cnt[e.x & 127], 1);
            atomicAdd(&deg[e.x & 127], __uint_as_float(e.y));
        }
        __syncthreads();
        if (tid < 128) sc[tid] = cnt[tid];
        __syncthreads();
        for (int d = 1; d < 128; d <<= 1) {
            int t2 = (tid >= d && tid < 128) ? sc[tid - d] : 0;
            __syncthreads();
            if (tid < 128) sc[tid] += t2;
            __syncthreads();
        }
        if (tid < 128) cur[tid] = sc[tid] - cnt[tid];   // exclusive
        __syncthreads();
#pragma unroll
        for (int k = 0; k < 12; ++k) {
            int i = base + tid + k * 256;
            if (i < end) {
                int kl = (int)(it[k].x & 127);
                int pos = atomicAdd(&cur[kl], 1);
                csr[base + pos] = (int)(it[k].x >> 7);
            }
        }
        for (int i = base + 3072 + tid; i < end; i += 256) {
            uint2 e = binned[i];
            int pos = atomicAdd(&cur[e.x & 127], 1);
            csr[base + pos] = (int)(e.x >> 7);
        }
        if (tid < 128) {
            int key = (vb << 7) + tid;
            off[key] = base + sc[tid] - cnt[tid];
            inv[key] = 1.0f / deg[tid];   // inf for deg 0: never gathered
        }
        // keys 100000..100095 (bin 781 padding) get off = TOT -> valid sentinel
    }
    __threadfence();
    grid.sync();

    // ---- phase 5: bf16 X tables (binned now dead; Xso/Xsi/Xb alias it) ----
    {
        int total = (int)(NF / 4);          // 400000
        for (int t = vb * 256 + tid; t < total; t += gridDim.x * 256) {
            int v = (t * 4) >> 5;           // F_IN = 32
            float so = inv[N_NODES + v];    // inv_o
            float si = inv[v];              // inv_i
            float4 val = *(const float4*)&X[t * 4];
            ushort4 a, b, c;
            a.x = f2bf(val.x * so); a.y = f2bf(val.y * so);
            a.z = f2bf(val.z * so); a.w = f2bf(val.w * so);
            b.x = f2bf(val.x * si); b.y = f2bf(val.y * si);
            b.z = f2bf(val.z * si); b.w = f2bf(val.w * si);
            c.x = f2bf(val.x);      c.y = f2bf(val.y);
            c.z = f2bf(val.z);      c.w = f2bf(val.w);
            *(ushort4*)&Xso[t * 4] = a;
            *(ushort4*)&Xsi[t * 4] = b;
            *(ushort4*)&Xb[t * 4]  = c;
        }
    }
}

// ---------------------------------------------------------------------------
// Gather propagation: plain sum over pre-scaled bf16 tables (uint = 2 ch).
// PLAIN cached loads (nt-loads poison L2 residency: round-10 +27us lesson).
// 16-lane key-groups (4 keys/wave), unroll 16/8/4/1.
// STEP 1: writes raw bf16 T1 (k_final) + pre-scaled bf16 T1s (step 2).
// STEP 2: folds Tx2 = 2*acc - X in-register, writes packed bf16 T2.
// ---------------------------------------------------------------------------
template<int STEP>
__global__ __launch_bounds__(256) void k_gather(const int* __restrict__ off,
                                                const int* __restrict__ csr,
                                                const float* __restrict__ inv,
                                                const float* __restrict__ X,
                                                const unsigned* __restrict__ hs_fwd,
                                                const unsigned* __restrict__ hs_rev,
                                                unsigned* __restrict__ out_fwd,
                                                unsigned* __restrict__ out_rev,
                                                unsigned* __restrict__ scl_fwd,
                                                unsigned* __restrict__ scl_rev) {
    int g    = blockIdx.x;
    int xcd  = g & 7;
    int slot = g >> 3;
    bool fwd = xcd < 4;
    int blk  = slot * 4 + (xcd & 3);          // block index within direction
    if (blk >= NBLK_DIR) return;
    int kg  = threadIdx.x >> 4;               // key group 0..15
    int f2  = threadIdx.x & 15;               // channel pair
    int key = blk * KPB + kg;
    int idx = fwd ? key : (N_NODES + key);
    const unsigned* hs = fwd ? hs_fwd : hs_rev;
    int beg = off[idx];
    int end = off[idx + 1];
    float aL0 = 0.f, aH0 = 0.f, aL1 = 0.f, aH1 = 0.f;
    int j = beg;
    for (; j + 15 < end; j += 16) {
        int s[16];
#pragma unroll
        for (int u = 0; u < 16; ++u) s[u] = csr[j + u];
        unsigned h[16];
#pragma unroll
        for (int u = 0; u < 16; ++u) h[u] = hs[s[u] * 16 + f2];
#pragma unroll
        for (int u = 0; u < 16; u += 2) {
            aL0 += bfLO(h[u]);     aH0 += bfHI(h[u]);
            aL1 += bfLO(h[u + 1]); aH1 += bfHI(h[u + 1]);
        }
    }
    for (; j + 7 < end; j += 8) {
        int s[8];
#pragma unroll
        for (int u = 0; u < 8; ++u) s[u] = csr[j + u];
        unsigned h[8];
#pragma unroll
        for (int u = 0; u < 8; ++u) h[u] = hs[s[u] * 16 + f2];
#pragma unroll
        for (int u = 0; u < 8; u += 2) {
            aL0 += bfLO(h[u]);     aH0 += bfHI(h[u]);
            aL1 += bfLO(h[u + 1]); aH1 += bfHI(h[u + 1]);
        }
    }
    for (; j + 3 < end; j += 4) {
        int s0 = csr[j], s1 = csr[j + 1], s2 = csr[j + 2], s3 = csr[j + 3];
        unsigned h0 = hs[s0 * 16 + f2], h1 = hs[s1 * 16 + f2];
        unsigned h2 = hs[s2 * 16 + f2], h3 = hs[s3 * 16 + f2];
        aL0 += bfLO(h0); aH0 += bfHI(h0); aL1 += bfLO(h1); aH1 += bfHI(h1);
        aL0 += bfLO(h2); aH0 += bfHI(h2); aL1 += bfLO(h3); aH1 += bfHI(h3);
    }
    for (; j < end; ++j) {
        unsigned h = hs[csr[j] * 16 + f2];
        aL0 += bfLO(h); aH0 += bfHI(h);
    }
    float aL = aL0 + aL1;
    float aH = aH0 + aH1;

    if (STEP == 1) {
        // next-step table scale: fwd node v -> inv_o[v] = inv[N+v]; rev -> inv_i[v]
        float sc = fwd ? inv[N_NODES + key] : inv[key];
        unsigned raw = ((unsigned)f2bf(aH) << 16) | f2bf(aL);
        unsigned scl = ((unsigned)f2bf(aH * sc) << 16) | f2bf(aL * sc);
        (fwd ? out_fwd : out_rev)[key * 16 + f2] = raw;
        (fwd ? scl_fwd : scl_rev)[key * 16 + f2] = scl;
    } else {
        float2 xv = *(const float2*)&X[key * 32 + f2 * 2];
        unsigned t2 = ((unsigned)f2bf(2.0f * aH - xv.y) << 16) | f2bf(2.0f * aL - xv.x);
        (fwd ? out_fwd : out_rev)[key * 16 + f2] = t2;
    }
}

// ---------------------------------------------------------------------------
// MFMA epilogue: [32 nodes x 160] x [160 x 128]. All five A-fragments load
// directly as bf16 s16x8 (Xb, T1o, T1i, T2o, T2i); B in registers from Wt.
// In-register gating; LDS only for relu'd H -> 64x12 head.
// ---------------------------------------------------------------------------
__global__ __launch_bounds__(256, 4) void k_final(
        const ushort* __restrict__ Xb,
        const ushort* __restrict__ T1o,
        const ushort* __restrict__ T1i,
        const ushort* __restrict__ T2o,
        const ushort* __restrict__ T2i,
        const ushort* __restrict__ Wt,
        const float* __restrict__ bz,
        const float* __restrict__ bh,
        const float* __restrict__ wlin,
        const float* __restrict__ blin,
        float* __restrict__ out) {
    __shared__ float r_lds[32][66];                    // 8448 B total LDS
    int tid   = threadIdx.x;
    int node0 = blockIdx.x * 32;
    int w  = tid >> 6;
    int l  = tid & 63;
    int lr = l & 15;
    int lg = l >> 4;
    int rt = w & 1;             // row tile (16 nodes)
    int cb = (w >> 1) * 32;     // col base within the 64 z (and 64 h) cols

    // --- B fragments in registers: t in {z-ct0, z-ct1, h-ct0, h-ct1} ---
    s16x8 bf[4][5];
#pragma unroll
    for (int t = 0; t < 4; ++t) {
        int col = cb + (t & 1) * 16 + lr + ((t >> 1) ? 64 : 0);
        const ushort* wp = Wt + col * C_FEAT + lg * 8;
#pragma unroll
        for (int kb = 0; kb < 5; ++kb)
            bf[t][kb] = *(const s16x8*)(wp + kb * 32);
    }

    // --- A fragments: five direct 16B bf16 loads (row clamped; tail masked) ---
    int row = node0 + rt * 16 + lr;
    if (row >= N_NODES) row = N_NODES - 1;
    int rbase = row * F_IN + lg * 8;
    s16x8 a[5];
    a[0] = *(const s16x8*)&Xb[rbase];
    a[1] = *(const s16x8*)&T1o[rbase];
    a[2] = *(const s16x8*)&T1i[rbase];
    a[3] = *(const s16x8*)&T2o[rbase];
    a[4] = *(const s16x8*)&T2i[rbase];

    // --- MFMA: 4 accs x 5 K-blocks ---
    f32x4 acc[4] = {};
#pragma unroll
    for (int kb = 0; kb < 5; ++kb) {
        acc[0] = __builtin_amdgcn_mfma_f32_16x16x32_bf16(a[kb], bf[0][kb], acc[0], 0, 0, 0);
        acc[1] = __builtin_amdgcn_mfma_f32_16x16x32_bf16(a[kb], bf[1][kb], acc[1], 0, 0, 0);
        acc[2] = __builtin_amdgcn_mfma_f32_16x16x32_bf16(a[kb], bf[2][kb], acc[2], 0, 0, 0);
        acc[3] = __builtin_amdgcn_mfma_f32_16x16x32_bf16(a[kb], bf[3][kb], acc[3], 0, 0, 0);
    }

    // --- in-register gating; D layout: col = lane&15, row = lg*4 + q ---
#pragma unroll
    for (int ct = 0; ct < 2; ++ct) {
        int o = cb + ct * 16 + lr;
        float bzv = bz[o];
        float bhv = bh[o];
#pragma unroll
        for (int qq = 0; qq < 4; ++qq) {
            float zp = acc[ct][qq] + bzv;
            float hp = acc[2 + ct][qq] + bhv;
            float z  = 1.0f / (1.0f + __expf(-zp));
            float e2 = __expf(2.0f * hp);
            float th = 1.0f - 2.0f / (e2 + 1.0f);    // tanh(hp)
            r_lds[rt * 16 + lg * 4 + qq][o] = fmaxf((1.0f - z) * th, 0.0f);
        }
    }
    __syncthreads();

    // --- 64x12 head ---
    for (int i = tid; i < 32 * PERIODS; i += 256) {
        int n = i / PERIODS;
        int p = i % PERIODS;
        int v = node0 + n;
        if (v < N_NODES) {
            float acc2 = blin[p];
#pragma unroll
            for (int oo = 0; oo < F_OUT; ++oo)
                acc2 = fmaf(r_lds[n][oo], wlin[oo * PERIODS + p], acc2);
            out[v * PERIODS + p] = acc2;
        }
    }
}

// ---------------------------------------------------------------------------
extern "C" void kernel_launch(void* const* d_in, const int* in_sizes, int n_in,
                              void* d_out, int out_size, void* d_ws, size_t ws_size,
                              hipStream_t stream) {
    const float* x    = (const float*)d_in[0];
    const int*   ei   = (const int*)d_in[1];
    const float* ew   = (const float*)d_in[2];
    const float* wz   = (const float*)d_in[3];
    const float* bz   = (const float*)d_in[4];
    // d_in[5], d_in[6] = w_r, b_r : provably unused (H0 == 0)
    const float* wh   = (const float*)d_in[7];
    const float* bh   = (const float*)d_in[8];
    const float* wlin = (const float*)d_in[9];
    const float* blin = (const float*)d_in[10];

    // workspace layout — all write-before-read; no memset. Xso/Xsi/Xb alias
    // the binned buffer (dead after build phase 4; phase 5 writes them).
    int*      histA  = (int*)d_ws;                     // [100096]
    int*      scanA  = histA + SCANA_N;                // [100096]
    int*      bsum   = scanA + SCANA_N;                // [512]
    uint2*    binned = (uint2*)(bsum + 512);           // [1.6M] 12.8 MB
    ushort*   Xso    = (ushort*)binned;                // [NF] aliases binned
    ushort*   Xsi    = Xso + NF;                       // [NF] aliases binned
    ushort*   Xb     = Xsi + NF;                       // [NF] aliases binned (9.6<=12.8MB)
    int*      csr    = (int*)(binned + TOT);           // [1.6M]
    int*      off    = csr + TOT;                      // [100100]
    float*    inv    = (float*)(off + 100100);         // [100096]
    ushort*   T1o_b  = (ushort*)(inv + SCANA_N);       // raw bf16 Tx1 (k_final)
    ushort*   T1i_b  = T1o_b + NF;
    ushort*   T1o_s  = T1i_b + NF;                     // pre-scaled bf16 (step 2)
    ushort*   T1i_s  = T1o_s + NF;
    ushort*   T2o_b  = T1i_s + NF;                     // bf16 Tx2 (k_final)
    ushort*   T2i_b  = T2o_b + NF;
    ushort*   Wt     = T2i_b + NF;                     // [128*160] bf16

    // fused CSR build + tables (cooperative: 5 internal grid syncs)
    void* bargs[] = { (void*)&ei, (void*)&ew, (void*)&wz, (void*)&wh, (void*)&Wt,
                      (void*)&histA, (void*)&scanA, (void*)&bsum,
                      (void*)&binned, (void*)&csr, (void*)&off, (void*)&inv,
                      (void*)&x, (void*)&Xso, (void*)&Xsi, (void*)&Xb };
    hipLaunchCooperativeKernel((void*)k_build, dim3(NBIN), dim3(256),
                               bargs, 0, stream);

    int ggrid = 8 * ((NBLK_DIR + 3) / 4);   // 6256 blocks, direction-split swizzle
    // step 1: Tx1 = prop(X): raw bf16 + pre-scaled bf16 outputs
    k_gather<1><<<ggrid, 256, 0, stream>>>(off, csr, inv, x,
                                           (const unsigned*)Xso, (const unsigned*)Xsi,
                                           (unsigned*)T1o_b, (unsigned*)T1i_b,
                                           (unsigned*)T1o_s, (unsigned*)T1i_s);
    // step 2: Tx2 = 2*prop(Tx1_s) - X, folded in-register, bf16 out
    k_gather<2><<<ggrid, 256, 0, stream>>>(off, csr, inv, x,
                                           (const unsigned*)T1o_s, (const unsigned*)T1i_s,
                                           (unsigned*)T2o_b, (unsigned*)T2i_b,
                                           nullptr, nullptr);

    k_final<<<(N_NODES + 31) / 32, 256, 0, stream>>>(Xb, T1o_b, T1i_b, T2o_b, T2i_b,
                                                     Wt, bz, bh, wlin, blin,
                                                     (float*)d_out);
}

// Round 13
// 127.979 us; speedup vs baseline: 6.9410x; 6.9410x over previous
//
#include <hip/hip_runtime.h>

#define N_NODES 50000
#define N_EDGES 800000
#define F_IN    32
#define F_OUT   64
#define PERIODS 12
#define C_FEAT  160   // [X, Tx1o, Tx1i, Tx2o, Tx2i] each 32 channels

#define NKEY    (2 * N_NODES)    // 100000 combined keys: fwd=col, rev=N+row
#define NBIN    782              // ceil(100000/128) — 128 keys per bin
#define NBLK_A  128
#define EPB     (N_EDGES / NBLK_A)   // 6250 edges per A-block (exact)
#define TOT     (2 * N_EDGES)        // 1.6M CSR entries
#define SCANA_N (NBIN * NBLK_A)      // 100096 = 391*256 exactly
#define SCANA_NB 391
#define KPB     16                   // keys per gather block (16-lane groups)
#define NBLK_DIR (N_NODES / KPB)     // 3125 gather blocks per direction
#define NF      ((size_t)N_NODES * F_IN)
#define PREP_BLKS ((128 * C_FEAT) / 256)   // 80

typedef __attribute__((ext_vector_type(8))) short s16x8;
typedef __attribute__((ext_vector_type(4))) float f32x4;

static __device__ __forceinline__ ushort f2bf(float f) {
    unsigned u = __float_as_uint(f);
    unsigned r = (u + 0x7FFFu + ((u >> 16) & 1u)) >> 16;   // RNE
    return (ushort)r;
}
static __device__ __forceinline__ float bfLO(unsigned h) {   // low bf16 channel
    return __uint_as_float(h << 16);
}
static __device__ __forceinline__ float bfHI(unsigned h) {   // high bf16 channel
    return __uint_as_float(h & 0xffff0000u);
}

// ---------------------------------------------------------------------------
// Pass A1 (blocks 0..127): per-block LDS histogram into 782 coarse bins.
// Blocks 128..207: weight prep — bf16 transposed Wt[o][k], o in [0,128):
// z cols then h cols; source (2,3,96,64), rows 32..95 dead (H0==0).
// (Round-12 lesson: do NOT fuse this chain cooperatively — grid.sync on
//  8 XCDs costs ~165us/barrier in cross-XCD coherence flushes.)
// ---------------------------------------------------------------------------
__global__ __launch_bounds__(256) void k_histA(const int* __restrict__ ei,
                                               int* __restrict__ hist,
                                               const float* __restrict__ wz,
                                               const float* __restrict__ wh,
                                               ushort* __restrict__ Wt) {
    __shared__ int h[NBIN];
    int tid = threadIdx.x, blk = blockIdx.x;
    if (blk >= NBLK_A) {                       // ---- prep part ----
        int t = (blk - NBLK_A) * 256 + tid;    // 0..20479 = 128*160
        int o = t / C_FEAT;
        int k = t % C_FEAT;
        int seg = k >> 5;
        int cc  = k & 31;
        const float* src = (o < 64) ? wz : wh;
        int oo = o & 63;
        float val;
        if (seg == 0)      val = src[(0 * 96 + cc) * 64 + oo] + src[(3 * 96 + cc) * 64 + oo];
        else if (seg == 1) val = src[(1 * 96 + cc) * 64 + oo];
        else if (seg == 2) val = src[(4 * 96 + cc) * 64 + oo];
        else if (seg == 3) val = src[(2 * 96 + cc) * 64 + oo];
        else               val = src[(5 * 96 + cc) * 64 + oo];
        Wt[t] = f2bf(val);
        return;
    }
    for (int i = tid; i < NBIN; i += 256) h[i] = 0;
    __syncthreads();
    int e0 = blk * EPB;
    for (int i = tid; i < EPB; i += 256) {
        int e = e0 + i;
        int r = ei[e];
        int c = ei[N_EDGES + e];
        atomicAdd(&h[c >> 7], 1);
        atomicAdd(&h[(N_NODES + r) >> 7], 1);
    }
    __syncthreads();
    for (int i = tid; i < NBIN; i += 256) hist[i * NBLK_A + blk] = h[i];
}

// ---------------------------------------------------------------------------
// Exclusive scan of hist[SCANA_N]; bsum folded in by consumers.
// ---------------------------------------------------------------------------
__global__ __launch_bounds__(256) void k_scan1(const int* __restrict__ cnt,
                                               int* __restrict__ scanA,
                                               int* __restrict__ bsum) {
    __shared__ int lds[256];
    int g = blockIdx.x * 256 + threadIdx.x;
    int v = (g < SCANA_N) ? cnt[g] : 0;
    int orig = v;
    lds[threadIdx.x] = v;
    __syncthreads();
    for (int d = 1; d < 256; d <<= 1) {
        int t = (threadIdx.x >= d) ? lds[threadIdx.x - d] : 0;
        __syncthreads();
        lds[threadIdx.x] += t;
        __syncthreads();
    }
    if (g < SCANA_N) scanA[g] = lds[threadIdx.x] - orig;   // exclusive, block-local
    if (threadIdx.x == 255) bsum[blockIdx.x] = lds[threadIdx.x];
}

__global__ __launch_bounds__(512) void k_scan2(int* __restrict__ bsum) {
    __shared__ int lds[512];
    int t = threadIdx.x;
    int v = (t < SCANA_NB) ? bsum[t] : 0;
    int orig = v;
    lds[t] = v;
    __syncthreads();
    for (int d = 1; d < 512; d <<= 1) {
        int x = (t >= d) ? lds[t - d] : 0;
        __syncthreads();
        lds[t] += x;
        __syncthreads();
    }
    if (t < SCANA_NB) bsum[t] = lds[t] - orig;             // exclusive
}

// ---------------------------------------------------------------------------
// Pass A3: multi-split — place 8B items (key_low7 | src<<7, w) into bins.
// ---------------------------------------------------------------------------
__global__ __launch_bounds__(256) void k_binA(const int* __restrict__ ei,
                                              const float* __restrict__ ew,
                                              const int* __restrict__ scanA,
                                              const int* __restrict__ bsum,
                                              uint2* __restrict__ binned) {
    __shared__ int cur[NBIN];
    int tid = threadIdx.x, blk = blockIdx.x;
    for (int i = tid; i < NBIN; i += 256) {
        int idx = i * NBLK_A + blk;
        cur[i] = scanA[idx] + bsum[idx >> 8];
    }
    __syncthreads();
    int e0 = blk * EPB;
    for (int i = tid; i < EPB; i += 256) {
        int e = e0 + i;
        int r = ei[e];
        int c = ei[N_EDGES + e];
        unsigned wb = __float_as_uint(ew[e]);
        int k1 = c;               // fwd: grouped by col, src = row
        int k2 = N_NODES + r;     // rev: grouped by row, src = col
        int p1 = atomicAdd(&cur[k1 >> 7], 1);
        binned[p1] = make_uint2((unsigned)((k1 & 127) | (r << 7)), wb);
        int p2 = atomicAdd(&cur[k2 >> 7], 1);
        binned[p2] = make_uint2((unsigned)((k2 & 127) | (c << 7)), wb);
    }
}

// ---------------------------------------------------------------------------
// Pass B: per-bin counting sort, SINGLE-PASS over global (items register-held,
// 12/thread = 3072 cap vs E[len]=2046, sigma~45; overflow re-read path for
// safety). Also degree sums -> inv[key], and off[key].
// ---------------------------------------------------------------------------
__global__ __launch_bounds__(256) void k_sortbin(const uint2* __restrict__ binned,
                                                 const int* __restrict__ scanA,
                                                 const int* __restrict__ bsum,
                                                 int* __restrict__ csr,
                                                 int* __restrict__ off,
                                                 float* __restrict__ inv) {
    __shared__ int cnt[128];
    __shared__ int sc[128];
    __shared__ int cur[128];
    __shared__ float deg[128];
    int tid = threadIdx.x;
    int b   = blockIdx.x;
    int i0 = b * NBLK_A;
    int base = scanA[i0] + bsum[i0 >> 8];
    int end;
    if (b + 1 < NBIN) {
        int i1 = (b + 1) * NBLK_A;
        end = scanA[i1] + bsum[i1 >> 8];
    } else end = TOT;
    if (tid < 128) { cnt[tid] = 0; deg[tid] = 0.0f; }
    __syncthreads();
    uint2 it[12];
#pragma unroll
    for (int k = 0; k < 12; ++k) {
        int i = base + tid + k * 256;
        if (i < end) it[k] = binned[i];
    }
#pragma unroll
    for (int k = 0; k < 12; ++k) {
        int i = base + tid + k * 256;
        if (i < end) {
            int kl = (int)(it[k].x & 127);
            atomicAdd(&cnt[kl], 1);
            atomicAdd(&deg[kl], __uint_as_float(it[k].y));
        }
    }
    // overflow path (len > 3072): statistically never, correct if hit
    for (int i = base + 3072 + tid; i < end; i += 256) {
        uint2 e = binned[i];
        atomicAdd(&cnt[e.x & 127], 1);
        atomicAdd(&deg[e.x & 127], __uint_as_float(e.y));
    }
    __syncthreads();
    if (tid < 128) sc[tid] = cnt[tid];
    __syncthreads();
    for (int d = 1; d < 128; d <<= 1) {
        int t = (tid >= d && tid < 128) ? sc[tid - d] : 0;
        __syncthreads();
        if (tid < 128) sc[tid] += t;
        __syncthreads();
    }
    if (tid < 128) cur[tid] = sc[tid] - cnt[tid];   // exclusive
    __syncthreads();
#pragma unroll
    for (int k = 0; k < 12; ++k) {
        int i = base + tid + k * 256;
        if (i < end) {
            int kl = (int)(it[k].x & 127);
            int pos = atomicAdd(&cur[kl], 1);
            csr[base + pos] = (int)(it[k].x >> 7);
        }
    }
    for (int i = base + 3072 + tid; i < end; i += 256) {
        uint2 e = binned[i];
        int pos = atomicAdd(&cur[e.x & 127], 1);
        csr[base + pos] = (int)(e.x >> 7);
    }
    if (tid < 128) {
        int key = (b << 7) + tid;
        off[key] = base + sc[tid] - cnt[tid];
        inv[key] = 1.0f / deg[tid];                  // inf for deg 0: never gathered
    }
    // keys 100000..100095 (bin 781 padding) get off = TOT -> valid sentinel.
}

// ---------------------------------------------------------------------------
// bf16 X tables (after CSR build; needs inv):
//   Xso = inv_o*X (fwd gather src), Xsi = inv_i*X (rev), Xb = raw X (k_final)
// ---------------------------------------------------------------------------
__global__ __launch_bounds__(256) void k_xbf(const float* __restrict__ X,
                                             const float* __restrict__ inv,
                                             ushort* __restrict__ Xso,
                                             ushort* __restrict__ Xsi,
                                             ushort* __restrict__ Xb) {
    int t = blockIdx.x * 256 + threadIdx.x;
    if (t * 4 >= (int)NF) return;
    int v = (t * 4) >> 5;                     // F_IN = 32, 4 | 32
    float so = inv[N_NODES + v];              // inv_o
    float si = inv[v];                        // inv_i
    float4 val = *(const float4*)&X[t * 4];
    ushort4 a, b, c;
    a.x = f2bf(val.x * so); a.y = f2bf(val.y * so);
    a.z = f2bf(val.z * so); a.w = f2bf(val.w * so);
    b.x = f2bf(val.x * si); b.y = f2bf(val.y * si);
    b.z = f2bf(val.z * si); b.w = f2bf(val.w * si);
    c.x = f2bf(val.x);      c.y = f2bf(val.y);
    c.z = f2bf(val.z);      c.w = f2bf(val.w);
    *(ushort4*)&Xso[t * 4] = a;
    *(ushort4*)&Xsi[t * 4] = b;
    *(ushort4*)&Xb[t * 4]  = c;
}

// ---------------------------------------------------------------------------
// Gather propagation: plain sum over pre-scaled bf16 tables (uint = 2 ch).
// PLAIN cached loads (nt-loads poison L2 residency: round-10 +27us lesson).
// 16-lane key-groups (4 keys/wave), unroll 16/8/4/1.
// STEP 1: writes raw bf16 T1 (k_final) + pre-scaled bf16 T1s (step 2).
// STEP 2: folds Tx2 = 2*acc - X in-register, writes packed bf16 T2.
// ---------------------------------------------------------------------------
template<int STEP>
__global__ __launch_bounds__(256) void k_gather(const int* __restrict__ off,
                                                const int* __restrict__ csr,
                                                const float* __restrict__ inv,
                                                const float* __restrict__ X,
                                                const unsigned* __restrict__ hs_fwd,
                                                const unsigned* __restrict__ hs_rev,
                                                unsigned* __restrict__ out_fwd,
                                                unsigned* __restrict__ out_rev,
                                                unsigned* __restrict__ scl_fwd,
                                                unsigned* __restrict__ scl_rev) {
    int g    = blockIdx.x;
    int xcd  = g & 7;
    int slot = g >> 3;
    bool fwd = xcd < 4;
    int blk  = slot * 4 + (xcd & 3);          // block index within direction
    if (blk >= NBLK_DIR) return;
    int kg  = threadIdx.x >> 4;               // key group 0..15
    int f2  = threadIdx.x & 15;               // channel pair
    int key = blk * KPB + kg;
    int idx = fwd ? key : (N_NODES + key);
    const unsigned* hs = fwd ? hs_fwd : hs_rev;
    int beg = off[idx];
    int end = off[idx + 1];
    float aL0 = 0.f, aH0 = 0.f, aL1 = 0.f, aH1 = 0.f;
    int j = beg;
    for (; j + 15 < end; j += 16) {
        int s[16];
#pragma unroll
        for (int u = 0; u < 16; ++u) s[u] = csr[j + u];
        unsigned h[16];
#pragma unroll
        for (int u = 0; u < 16; ++u) h[u] = hs[s[u] * 16 + f2];
#pragma unroll
        for (int u = 0; u < 16; u += 2) {
            aL0 += bfLO(h[u]);     aH0 += bfHI(h[u]);
            aL1 += bfLO(h[u + 1]); aH1 += bfHI(h[u + 1]);
        }
    }
    for (; j + 7 < end; j += 8) {
        int s[8];
#pragma unroll
        for (int u = 0; u < 8; ++u) s[u] = csr[j + u];
        unsigned h[8];
#pragma unroll
        for (int u = 0; u < 8; ++u) h[u] = hs[s[u] * 16 + f2];
#pragma unroll
        for (int u = 0; u < 8; u += 2) {
            aL0 += bfLO(h[u]);     aH0 += bfHI(h[u]);
            aL1 += bfLO(h[u + 1]); aH1 += bfHI(h[u + 1]);
        }
    }
    for (; j + 3 < end; j += 4) {
        int s0 = csr[j], s1 = csr[j + 1], s2 = csr[j + 2], s3 = csr[j + 3];
        unsigned h0 = hs[s0 * 16 + f2], h1 = hs[s1 * 16 + f2];
        unsigned h2 = hs[s2 * 16 + f2], h3 = hs[s3 * 16 + f2];
        aL0 += bfLO(h0); aH0 += bfHI(h0); aL1 += bfLO(h1); aH1 += bfHI(h1);
        aL0 += bfLO(h2); aH0 += bfHI(h2); aL1 += bfLO(h3); aH1 += bfHI(h3);
    }
    for (; j < end; ++j) {
        unsigned h = hs[csr[j] * 16 + f2];
        aL0 += bfLO(h); aH0 += bfHI(h);
    }
    float aL = aL0 + aL1;
    float aH = aH0 + aH1;

    if (STEP == 1) {
        // next-step table scale: fwd node v -> inv_o[v] = inv[N+v]; rev -> inv_i[v]
        float sc = fwd ? inv[N_NODES + key] : inv[key];
        unsigned raw = ((unsigned)f2bf(aH) << 16) | f2bf(aL);
        unsigned scl = ((unsigned)f2bf(aH * sc) << 16) | f2bf(aL * sc);
        (fwd ? out_fwd : out_rev)[key * 16 + f2] = raw;
        (fwd ? scl_fwd : scl_rev)[key * 16 + f2] = scl;
    } else {
        float2 xv = *(const float2*)&X[key * 32 + f2 * 2];
        unsigned t2 = ((unsigned)f2bf(2.0f * aH - xv.y) << 16) | f2bf(2.0f * aL - xv.x);
        (fwd ? out_fwd : out_rev)[key * 16 + f2] = t2;
    }
}

// ---------------------------------------------------------------------------
// MFMA epilogue: [32 nodes x 160] x [160 x 128]. All five A-fragments load
// directly as bf16 s16x8 (Xb, T1o, T1i, T2o, T2i); B in registers from Wt.
// In-register gating; LDS only for relu'd H -> 64x12 head.
// ---------------------------------------------------------------------------
__global__ __launch_bounds__(256, 4) void k_final(
        const ushort* __restrict__ Xb,
        const ushort* __restrict__ T1o,
        const ushort* __restrict__ T1i,
        const ushort* __restrict__ T2o,
        const ushort* __restrict__ T2i,
        const ushort* __restrict__ Wt,
        const float* __restrict__ bz,
        const float* __restrict__ bh,
        const float* __restrict__ wlin,
        const float* __restrict__ blin,
        float* __restrict__ out) {
    __shared__ float r_lds[32][66];                    // 8448 B total LDS
    int tid   = threadIdx.x;
    int node0 = blockIdx.x * 32;
    int w  = tid >> 6;
    int l  = tid & 63;
    int lr = l & 15;
    int lg = l >> 4;
    int rt = w & 1;             // row tile (16 nodes)
    int cb = (w >> 1) * 32;     // col base within the 64 z (and 64 h) cols

    // --- B fragments in registers: t in {z-ct0, z-ct1, h-ct0, h-ct1} ---
    s16x8 bf[4][5];
#pragma unroll
    for (int t = 0; t < 4; ++t) {
        int col = cb + (t & 1) * 16 + lr + ((t >> 1) ? 64 : 0);
        const ushort* wp = Wt + col * C_FEAT + lg * 8;
#pragma unroll
        for (int kb = 0; kb < 5; ++kb)
            bf[t][kb] = *(const s16x8*)(wp + kb * 32);
    }

    // --- A fragments: five direct 16B bf16 loads (row clamped; tail masked) ---
    int row = node0 + rt * 16 + lr;
    if (row >= N_NODES) row = N_NODES - 1;
    int rbase = row * F_IN + lg * 8;
    s16x8 a[5];
    a[0] = *(const s16x8*)&Xb[rbase];
    a[1] = *(const s16x8*)&T1o[rbase];
    a[2] = *(const s16x8*)&T1i[rbase];
    a[3] = *(const s16x8*)&T2o[rbase];
    a[4] = *(const s16x8*)&T2i[rbase];

    // --- MFMA: 4 accs x 5 K-blocks ---
    f32x4 acc[4] = {};
#pragma unroll
    for (int kb = 0; kb < 5; ++kb) {
        acc[0] = __builtin_amdgcn_mfma_f32_16x16x32_bf16(a[kb], bf[0][kb], acc[0], 0, 0, 0);
        acc[1] = __builtin_amdgcn_mfma_f32_16x16x32_bf16(a[kb], bf[1][kb], acc[1], 0, 0, 0);
        acc[2] = __builtin_amdgcn_mfma_f32_16x16x32_bf16(a[kb], bf[2][kb], acc[2], 0, 0, 0);
        acc[3] = __builtin_amdgcn_mfma_f32_16x16x32_bf16(a[kb], bf[3][kb], acc[3], 0, 0, 0);
    }

    // --- in-register gating; D layout: col = lane&15, row = lg*4 + q ---
#pragma unroll
    for (int ct = 0; ct < 2; ++ct) {
        int o = cb + ct * 16 + lr;
        float bzv = bz[o];
        float bhv = bh[o];
#pragma unroll
        for (int qq = 0; qq < 4; ++qq) {
            float zp = acc[ct][qq] + bzv;
            float hp = acc[2 + ct][qq] + bhv;
            float z  = 1.0f / (1.0f + __expf(-zp));
            float e2 = __expf(2.0f * hp);
            float th = 1.0f - 2.0f / (e2 + 1.0f);    // tanh(hp)
            r_lds[rt * 16 + lg * 4 + qq][o] = fmaxf((1.0f - z) * th, 0.0f);
        }
    }
    __syncthreads();

    // --- 64x12 head ---
    for (int i = tid; i < 32 * PERIODS; i += 256) {
        int n = i / PERIODS;
        int p = i % PERIODS;
        int v = node0 + n;
        if (v < N_NODES) {
            float acc2 = blin[p];
#pragma unroll
            for (int oo = 0; oo < F_OUT; ++oo)
                acc2 = fmaf(r_lds[n][oo], wlin[oo * PERIODS + p], acc2);
            out[v * PERIODS + p] = acc2;
        }
    }
}

// ---------------------------------------------------------------------------
extern "C" void kernel_launch(void* const* d_in, const int* in_sizes, int n_in,
                              void* d_out, int out_size, void* d_ws, size_t ws_size,
                              hipStream_t stream) {
    const float* x    = (const float*)d_in[0];
    const int*   ei   = (const int*)d_in[1];
    const float* ew   = (const float*)d_in[2];
    const float* wz   = (const float*)d_in[3];
    const float* bz   = (const float*)d_in[4];
    // d_in[5], d_in[6] = w_r, b_r : provably unused (H0 == 0)
    const float* wh   = (const float*)d_in[7];
    const float* bh   = (const float*)d_in[8];
    const float* wlin = (const float*)d_in[9];
    const float* blin = (const float*)d_in[10];

    // workspace layout — all write-before-read; no memset. Xso/Xsi/Xb alias
    // the binned buffer (dead after k_sortbin; k_xbf runs after it; 9.6<=12.8MB).
    int*      histA  = (int*)d_ws;                     // [100096]
    int*      scanA  = histA + SCANA_N;                // [100096]
    int*      bsum   = scanA + SCANA_N;                // [512]
    uint2*    binned = (uint2*)(bsum + 512);           // [1.6M] 12.8 MB
    ushort*   Xso    = (ushort*)binned;                // [NF] aliases binned
    ushort*   Xsi    = Xso + NF;                       // [NF] aliases binned
    ushort*   Xb     = Xsi + NF;                       // [NF] aliases binned
    int*      csr    = (int*)(binned + TOT);           // [1.6M]
    int*      off    = csr + TOT;                      // [100100]
    float*    inv    = (float*)(off + 100100);         // [100096]
    ushort*   T1o_b  = (ushort*)(inv + SCANA_N);       // raw bf16 Tx1 (k_final)
    ushort*   T1i_b  = T1o_b + NF;
    ushort*   T1o_s  = T1i_b + NF;                     // pre-scaled bf16 (step 2)
    ushort*   T1i_s  = T1o_s + NF;
    ushort*   T2o_b  = T1i_s + NF;                     // bf16 Tx2 (k_final)
    ushort*   T2i_b  = T2o_b + NF;
    ushort*   Wt     = T2i_b + NF;                     // [128*160] bf16

    // CSR build: histogram(+weight prep) -> scan -> multi-split -> bin sort
    k_histA<<<NBLK_A + PREP_BLKS, 256, 0, stream>>>(ei, histA, wz, wh, Wt);
    k_scan1<<<SCANA_NB, 256, 0, stream>>>(histA, scanA, bsum);
    k_scan2<<<1, 512, 0, stream>>>(bsum);
    k_binA<<<NBLK_A, 256, 0, stream>>>(ei, ew, scanA, bsum, binned);
    k_sortbin<<<NBIN, 256, 0, stream>>>(binned, scanA, bsum, csr, off, inv);

    // bf16 X tables (needs inv; binned now dead)
    k_xbf<<<((int)NF / 4 + 255) / 256, 256, 0, stream>>>(x, inv, Xso, Xsi, Xb);

    int ggrid = 8 * ((NBLK_DIR + 3) / 4);   // 6256 blocks, direction-split swizzle
    // step 1: Tx1 = prop(X): raw bf16 + pre-scaled bf16 outputs
    k_gather<1><<<ggrid, 256, 0, stream>>>(off, csr, inv, x,
                                           (const unsigned*)Xso, (const unsigned*)Xsi,
                                           (unsigned*)T1o_b, (unsigned*)T1i_b,
                                           (unsigned*)T1o_s, (unsigned*)T1i_s);
    // step 2: Tx2 = 2*prop(Tx1_s) - X, folded in-register, bf16 out
    k_gather<2><<<ggrid, 256, 0, stream>>>(off, csr, inv, x,
                                           (const unsigned*)T1o_s, (const unsigned*)T1i_s,
                                           (unsigned*)T2o_b, (unsigned*)T2i_b,
                                           nullptr, nullptr);

    k_final<<<(N_NODES + 31) / 32, 256, 0, stream>>>(Xb, T1o_b, T1i_b, T2o_b, T2i_b,
                                                     Wt, bz, bh, wlin, blin,
                                                     (float*)d_out);
}